// Round 17
// baseline (192.031 us; speedup 1.0000x reference)
//
#include <hip/hip_runtime.h>
#include <hip/hip_fp16.h>
#include <math.h>

#define NPROJ 96
#define NANG  96
#define DET   192
#define NPIX  16384            // 128*128
#define SLICE (NANG*DET)       // 18432

// DSD/DU = DSD/DV = 1000/3.5
#define KPROJ 285.7142857142857f
#define ACH   16               // bp2d angle chunk staged in LDS

__device__ __forceinline__ float frcp(float x) { return __builtin_amdgcn_rcpf(x); }

__device__ __forceinline__ float ffract(float x) {
#if __has_builtin(__builtin_amdgcn_fractf)
    return __builtin_amdgcn_fractf(x);
#else
    return x - floorf(x);
#endif
}

typedef __fp16 h2 __attribute__((ext_vector_type(2)));

__device__ __forceinline__ unsigned pack2(float a, float b) {
    h2 p = __builtin_amdgcn_cvt_pkrtz(a, b);
    return __builtin_bit_cast(unsigned, p);
}
__device__ __forceinline__ h2 as_h2(unsigned u) { return __builtin_bit_cast(h2, u); }

#if __has_builtin(__builtin_amdgcn_fdot2)
#define FDOT2(a, b, c) __builtin_amdgcn_fdot2((a), (b), (c), false)
#else
__device__ __forceinline__ float FDOT2(h2 a, h2 b, float c) {
    return c + (float)a[0] * (float)b[0] + (float)a[1] * (float)b[1];
}
#endif

// ---------------------------------------------------------------------------
// K1: deriv = grad_lastdim(sino * weight) -> DIFFERENCE pairs:
// derivp[row][d] = half2(g[d], g[d+1]-g[d])  =>  lerp weight is (1, f).
// ---------------------------------------------------------------------------
__global__ __launch_bounds__(192) void k_deriv(const float* __restrict__ sino,
                                               const float* __restrict__ wgt,
                                               unsigned* __restrict__ derivp) {
    __shared__ float row[DET];
    const int r = blockIdx.x;          // p*96 + a
    const int d = threadIdx.x;         // 0..191
    const int base = r * DET + d;
    row[d] = sino[base] * wgt[base];
    __syncthreads();
    auto grad = [&](int i) -> float {
        i = (i > DET-1) ? DET-1 : i;
        if (i == 0)       return row[1] - row[0];
        if (i == DET-1)   return row[DET-1] - row[DET-2];
        return 0.5f * (row[i+1] - row[i-1]);
    };
    const float g0 = grad(d), g1 = grad(d+1);
    derivp[base] = pack2(g0, g1 - g0);
}

// ---------------------------------------------------------------------------
// K2: 2D backprojection + cosine weighting — LDS-GATHER version:
// the global-gather pipe costs ~19 cyc/wave-load (calibrated r4..r13);
// ds_read_b32 costs ~5.8 and our span (<=64 consecutive dwords across the
// wave) is <=2-way bank aliasing = free. Stage 16-angle chunks (12.3 KB)
// and gather from LDS: 1 ds_read_b32 + fdot2 per sample, diff-pair
// weights (1, f). Lane map: stride-256 (r13 winner) — lane-adjacent
// threads = consecutive pixels. grid (96 p, 32 chunks), block 256.
// Epilogue writes every-v QUAD layout in DIFFERENCE form (unchanged):
//   wq[p][v][u] = uint4 of dpr(v..v+3,u), dpr = (w[v][u], w[v][u+1]-w[v][u]).
// pos in [5.7,185.3] -> no masks.
// ---------------------------------------------------------------------------
__global__ __launch_bounds__(256) void k_bp2d(const unsigned* __restrict__ derivp,
                                              unsigned* __restrict__ wq_dw) {
    __shared__ float sc[NANG], ss[NANG];
    __shared__ unsigned sd[ACH * DET];   // 12288 B staged diff-pairs
    __shared__ float buf[512];
    const int p   = blockIdx.x;
    const int tid = threadIdx.x;

    if (tid < NANG) {
        float s_, c_;
        sincosf((float)tid * (float)(3.14159265358979323846 / 96.0), &s_, &c_);
        sc[tid] = c_; ss[tid] = s_;
    }

    const int pixbase = blockIdx.y * 512;
    float acc[2], fx[2], fy[2];
    #pragma unroll
    for (int i = 0; i < 2; ++i) {
        const int pix = pixbase + i*256 + tid;
        fx[i] = (float)(pix & 127) - 63.5f;
        fy[i] = (float)(pix >> 7)  - 63.5f;
        acc[i] = 0.0f;
    }

    const float4* src = (const float4*)(derivp + p * SLICE);
    for (int c = 0; c < NANG/ACH; ++c) {
        // stage 16 angle-rows: 3072 dwords = 768 float4 = 3 per thread
        {
            float4* dst4 = (float4*)sd;
            const float4* s4 = src + c * (ACH*DET/4);
            #pragma unroll
            for (int i = 0; i < 3; ++i) dst4[tid + i*256] = s4[tid + i*256];
        }
        __syncthreads();   // staging (and, first iter, trig) ready

        const unsigned* rowp = sd;
        for (int la = 0; la < ACH; ++la, rowp += DET) {
            const int a = c * ACH + la;
            const float cb = sc[a], sb = ss[a];
            #pragma unroll
            for (int i = 0; i < 2; ++i) {
                const float pos = fmaf(cb, fx[i], fmaf(sb, fy[i], 95.5f));
                const int   i0  = (int)pos;            // pos > 0 always
                const float f   = ffract(pos);
                acc[i] = FDOT2(as_h2(rowp[i0]), as_h2(pack2(1.0f, f)), acc[i]);
            }
        }
        __syncthreads();   // consumed; safe to overwrite sd
    }

    #pragma unroll
    for (int i = 0; i < 2; ++i) {
        const float w = 1000.0f * rsqrtf(1000000.0f + fx[i]*fx[i] + fy[i]*fy[i]);
        buf[i*256 + tid] = acc[i] * w;
    }
    __syncthreads();

    // epilogue: difference-pair of row v lands in slot k of quad v-k, k=0..3
    unsigned* sq = wq_dw + p * (NPIX * 4);
    #pragma unroll
    for (int i = 0; i < 2; ++i) {
        const int l   = i*256 + tid;
        const int pix = pixbase + l;
        const int u   = pix & 127;
        const int v   = pix >> 7;
        const float v0 = buf[l];
        const float v1 = (u < 127) ? buf[l + 1] : 0.0f;   // u=127 pair unused
        const unsigned pr = pack2(v0, v1 - v0);
        #pragma unroll
        for (int k = 0; k < 4; ++k) {
            const int vb = v - k;
            if (vb >= 0) sq[(((vb << 7) + u) << 2) + k] = pr;
        }
    }
}

// ---------------------------------------------------------------------------
// K3: 3D cone-beam backprojection + PReLU — r13/r16 winner, UNCHANGED:
// every-v quad loads, ONE dwordx4 per z-pair; diff-pair u-weights
// (w2, fu*w2). grid (64 y-pairs, 32 z-chunks) = 2048 blocks = 32 waves/CU.
// pu in [11,116], pv in [19,108] -> no masks.
// ---------------------------------------------------------------------------
__global__ __launch_bounds__(256) void k_bp3d_q(const uint4* __restrict__ wq,
                                                const float* __restrict__ prelu,
                                                float* __restrict__ out) {
    __shared__ float sc[NPROJ], ss[NPROJ];
    const int tid = threadIdx.x;
    const int x   = tid & 127;
    const int y   = (blockIdx.x << 1) | (tid >> 7);
    const int z0  = blockIdx.y << 2;

    if (tid < NPROJ) {
        float s_, c_;
        sincosf((float)tid * (float)(2.0 * 3.14159265358979323846 / 96.0), &s_, &c_);
        sc[tid] = c_; ss[tid] = s_;
    }

    const float fx  = (float)x - 63.5f;
    const float fy  = (float)y - 63.5f;
    const float zlo = (float)z0 - 63.5f;

    float acc[4];
    #pragma unroll
    for (int j = 0; j < 4; ++j) acc[j] = 0.0f;

    __syncthreads();   // trig ready — the only barrier

    const uint4* bb = wq;                // per-beta slice = 128*128 uint4
    for (int b = 0; b < NPROJ; ++b, bb += NPIX) {
        const float cb    = sc[b], sb = ss[b];
        const float t     = fmaf(fx, cb,  fy * sb);
        const float sdist = fmaf(fy, cb, -fx * sb);
        const float invr  = frcp(500.0f + t);
        const float pu    = fmaf(KPROJ * sdist, invr, 63.5f);
        const int   iu0   = (int)pu;             // pu in [11, 116]
        const float fu    = ffract(pu);
        float w2 = 1000.0f * invr; w2 *= w2;
        const float Kz    = KPROJ * invr;
        const h2    wuw   = as_h2(pack2(w2, fu * w2));   // diff-pair weights

        #pragma unroll
        for (int pr2 = 0; pr2 < 2; ++pr2) {      // z-pairs (0,1), (2,3)
            const float pvA = fmaf(Kz, zlo + (float)(2*pr2), 63.5f);
            const float pvB = pvA + Kz;
            const int   ivA = (int)pvA;          // pv in [19, 108]
            const int   ivB = (int)pvB;          // ivA or ivA+1
            const float fvA = ffract(pvA);
            const float fvB = ffract(pvB);
            const uint4 q   = bb[(ivA << 7) + iu0];   // rows ivA..ivA+3
            const int   d   = ivB - ivA;              // 0 or 1
            const float tA  = FDOT2(as_h2(q.x), wuw, 0.0f);
            const float bA  = FDOT2(as_h2(q.y), wuw, 0.0f);
            acc[2*pr2]     += fmaf(fvA, bA - tA, tA);
            const unsigned tBv = d ? q.y : q.x;
            const unsigned bBv = d ? q.z : q.y;
            const float tB  = FDOT2(as_h2(tBv), wuw, 0.0f);
            const float bB  = FDOT2(as_h2(bBv), wuw, 0.0f);
            acc[2*pr2 + 1] += fmaf(fvB, bB - tB, tB);
        }
    }

    const float a = prelu[0];
    #pragma unroll
    for (int j = 0; j < 4; ++j) {
        const float v = acc[j];
        out[((z0 + j) << 14) + (y << 7) + x] = (v >= 0.0f) ? v : a * v;
    }
}

// ---------------------------------------------------------------------------
extern "C" void kernel_launch(void* const* d_in, const int* in_sizes, int n_in,
                              void* d_out, int out_size, void* d_ws, size_t ws_size,
                              hipStream_t stream) {
    const float* sino  = (const float*)d_in[0];   // (1,1,96,96,192)
    const float* wgt   = (const float*)d_in[1];   // (1,96,96,192)
    const float* prelu = (const float*)d_in[2];   // (1,)
    float* out = (float*)d_out;                   // 128^3 floats

    unsigned* wq_dw  = (unsigned*)d_ws;                        // 25.17 MB quads
    unsigned* derivp = wq_dw + (size_t)NPROJ * NPIX * 4;       // 7.08 MB pairs

    k_deriv<<<dim3(NPROJ * NANG), dim3(192), 0, stream>>>(sino, wgt, derivp);
    k_bp2d <<<dim3(NPROJ, 32),    dim3(256), 0, stream>>>(derivp, wq_dw);
    k_bp3d_q<<<dim3(64, 32),      dim3(256), 0, stream>>>((const uint4*)wq_dw, prelu, out);
}

// Round 18
// 190.064 us; speedup vs baseline: 1.0103x; 1.0103x over previous
//
#include <hip/hip_runtime.h>
#include <hip/hip_fp16.h>
#include <math.h>

#define NPROJ 96
#define NANG  96
#define DET   192
#define NPIX  16384            // 128*128
#define SLICE (NANG*DET)       // 18432

// DSD/DU = DSD/DV = 1000/3.5
#define KPROJ 285.7142857142857f

__device__ __forceinline__ float frcp(float x) { return __builtin_amdgcn_rcpf(x); }

__device__ __forceinline__ float ffract(float x) {
#if __has_builtin(__builtin_amdgcn_fractf)
    return __builtin_amdgcn_fractf(x);
#else
    return x - floorf(x);
#endif
}

typedef __fp16 h2 __attribute__((ext_vector_type(2)));

__device__ __forceinline__ unsigned pack2(float a, float b) {
    h2 p = __builtin_amdgcn_cvt_pkrtz(a, b);
    return __builtin_bit_cast(unsigned, p);
}
__device__ __forceinline__ h2 as_h2(unsigned u) { return __builtin_bit_cast(h2, u); }

#if __has_builtin(__builtin_amdgcn_fdot2)
#define FDOT2(a, b, c) __builtin_amdgcn_fdot2((a), (b), (c), false)
#else
__device__ __forceinline__ float FDOT2(h2 a, h2 b, float c) {
    return c + (float)a[0] * (float)b[0] + (float)a[1] * (float)b[1];
}
#endif

// ---------------------------------------------------------------------------
// K1: deriv = grad_lastdim(sino * weight) -> DIFFERENCE pairs:
// derivp[row][d] = half2(g[d], g[d+1]-g[d])  =>  lerp weight is (1, f).
// ---------------------------------------------------------------------------
__global__ __launch_bounds__(192) void k_deriv(const float* __restrict__ sino,
                                               const float* __restrict__ wgt,
                                               unsigned* __restrict__ derivp) {
    __shared__ float row[DET];
    const int r = blockIdx.x;          // p*96 + a
    const int d = threadIdx.x;         // 0..191
    const int base = r * DET + d;
    row[d] = sino[base] * wgt[base];
    __syncthreads();
    auto grad = [&](int i) -> float {
        i = (i > DET-1) ? DET-1 : i;
        if (i == 0)       return row[1] - row[0];
        if (i == DET-1)   return row[DET-1] - row[DET-2];
        return 0.5f * (row[i+1] - row[i-1]);
    };
    const float g0 = grad(d), g1 = grad(d+1);
    derivp[base] = pack2(g0, g1 - g0);
}

// ---------------------------------------------------------------------------
// K2: 2D backprojection + cosine weighting — r16 WINNER (global gathers):
// 2 px/thread at STRIDE 256 (lane-adjacent threads = consecutive pixels ->
// minimal wave gather span). Diff-pair weights (1, f). 1 dword gather per
// px-angle — at the gather-pipe/VALU equilibrium (r17 LDS variant: -3 us).
// Epilogue writes every-v QUAD layout in DIFFERENCE form:
//   wq[p][v][u] = uint4 of dpr(v..v+3,u), dpr = (w[v][u], w[v][u+1]-w[v][u]).
// grid (96 p, 32 chunks), block 256. pos in [5.7,185.3] -> no masks.
// ---------------------------------------------------------------------------
__global__ __launch_bounds__(256) void k_bp2d(const unsigned* __restrict__ derivp,
                                              unsigned* __restrict__ wq_dw) {
    __shared__ float sc[NANG], ss[NANG];
    __shared__ float buf[512];
    const int p   = blockIdx.x;
    const int tid = threadIdx.x;

    if (tid < NANG) {
        float s_, c_;
        sincosf((float)tid * (float)(3.14159265358979323846 / 96.0), &s_, &c_);
        sc[tid] = c_; ss[tid] = s_;
    }

    const int pixbase = blockIdx.y * 512;
    float acc[2], fx[2], fy[2];
    #pragma unroll
    for (int i = 0; i < 2; ++i) {
        const int pix = pixbase + i*256 + tid;
        fx[i] = (float)(pix & 127) - 63.5f;
        fy[i] = (float)(pix >> 7)  - 63.5f;
        acc[i] = 0.0f;
    }
    __syncthreads();   // trig ready

    const unsigned* rowp = derivp + p * SLICE;   // advances by DET per angle
    for (int a = 0; a < NANG; ++a, rowp += DET) {
        const float cb = sc[a], sb = ss[a];
        #pragma unroll
        for (int i = 0; i < 2; ++i) {
            const float pos = fmaf(cb, fx[i], fmaf(sb, fy[i], 95.5f));
            const int   i0  = (int)pos;            // pos > 0 always
            const float f   = ffract(pos);
            acc[i] = FDOT2(as_h2(rowp[i0]), as_h2(pack2(1.0f, f)), acc[i]);
        }
    }

    #pragma unroll
    for (int i = 0; i < 2; ++i) {
        const float w = 1000.0f * rsqrtf(1000000.0f + fx[i]*fx[i] + fy[i]*fy[i]);
        buf[i*256 + tid] = acc[i] * w;
    }
    __syncthreads();

    // epilogue: difference-pair of row v lands in slot k of quad v-k, k=0..3
    unsigned* sq = wq_dw + p * (NPIX * 4);
    #pragma unroll
    for (int i = 0; i < 2; ++i) {
        const int l   = i*256 + tid;
        const int pix = pixbase + l;
        const int u   = pix & 127;
        const int v   = pix >> 7;
        const float v0 = buf[l];
        const float v1 = (u < 127) ? buf[l + 1] : 0.0f;   // u=127 pair unused
        const unsigned pr = pack2(v0, v1 - v0);
        #pragma unroll
        for (int k = 0; k < 4; ++k) {
            const int vb = v - k;
            if (vb >= 0) sq[(((vb << 7) + u) << 2) + k] = pr;
        }
    }
}

// ---------------------------------------------------------------------------
// K3: 3D cone-beam backprojection + PReLU — r13/r16 winner, UNCHANGED:
// every-v quad loads, ONE dwordx4 per z-pair; diff-pair u-weights
// (w2, fu*w2). grid (64 y-pairs, 32 z-chunks) = 2048 blocks = 32 waves/CU.
// pu in [11,116], pv in [19,108] -> no masks.
// ---------------------------------------------------------------------------
__global__ __launch_bounds__(256) void k_bp3d_q(const uint4* __restrict__ wq,
                                                const float* __restrict__ prelu,
                                                float* __restrict__ out) {
    __shared__ float sc[NPROJ], ss[NPROJ];
    const int tid = threadIdx.x;
    const int x   = tid & 127;
    const int y   = (blockIdx.x << 1) | (tid >> 7);
    const int z0  = blockIdx.y << 2;

    if (tid < NPROJ) {
        float s_, c_;
        sincosf((float)tid * (float)(2.0 * 3.14159265358979323846 / 96.0), &s_, &c_);
        sc[tid] = c_; ss[tid] = s_;
    }

    const float fx  = (float)x - 63.5f;
    const float fy  = (float)y - 63.5f;
    const float zlo = (float)z0 - 63.5f;

    float acc[4];
    #pragma unroll
    for (int j = 0; j < 4; ++j) acc[j] = 0.0f;

    __syncthreads();   // trig ready — the only barrier

    const uint4* bb = wq;                // per-beta slice = 128*128 uint4
    for (int b = 0; b < NPROJ; ++b, bb += NPIX) {
        const float cb    = sc[b], sb = ss[b];
        const float t     = fmaf(fx, cb,  fy * sb);
        const float sdist = fmaf(fy, cb, -fx * sb);
        const float invr  = frcp(500.0f + t);
        const float pu    = fmaf(KPROJ * sdist, invr, 63.5f);
        const int   iu0   = (int)pu;             // pu in [11, 116]
        const float fu    = ffract(pu);
        float w2 = 1000.0f * invr; w2 *= w2;
        const float Kz    = KPROJ * invr;
        const h2    wuw   = as_h2(pack2(w2, fu * w2));   // diff-pair weights

        #pragma unroll
        for (int pr2 = 0; pr2 < 2; ++pr2) {      // z-pairs (0,1), (2,3)
            const float pvA = fmaf(Kz, zlo + (float)(2*pr2), 63.5f);
            const float pvB = pvA + Kz;
            const int   ivA = (int)pvA;          // pv in [19, 108]
            const int   ivB = (int)pvB;          // ivA or ivA+1
            const float fvA = ffract(pvA);
            const float fvB = ffract(pvB);
            const uint4 q   = bb[(ivA << 7) + iu0];   // rows ivA..ivA+3
            const int   d   = ivB - ivA;              // 0 or 1
            const float tA  = FDOT2(as_h2(q.x), wuw, 0.0f);
            const float bA  = FDOT2(as_h2(q.y), wuw, 0.0f);
            acc[2*pr2]     += fmaf(fvA, bA - tA, tA);
            const unsigned tBv = d ? q.y : q.x;
            const unsigned bBv = d ? q.z : q.y;
            const float tB  = FDOT2(as_h2(tBv), wuw, 0.0f);
            const float bB  = FDOT2(as_h2(bBv), wuw, 0.0f);
            acc[2*pr2 + 1] += fmaf(fvB, bB - tB, tB);
        }
    }

    const float a = prelu[0];
    #pragma unroll
    for (int j = 0; j < 4; ++j) {
        const float v = acc[j];
        out[((z0 + j) << 14) + (y << 7) + x] = (v >= 0.0f) ? v : a * v;
    }
}

// ---------------------------------------------------------------------------
extern "C" void kernel_launch(void* const* d_in, const int* in_sizes, int n_in,
                              void* d_out, int out_size, void* d_ws, size_t ws_size,
                              hipStream_t stream) {
    const float* sino  = (const float*)d_in[0];   // (1,1,96,96,192)
    const float* wgt   = (const float*)d_in[1];   // (1,96,96,192)
    const float* prelu = (const float*)d_in[2];   // (1,)
    float* out = (float*)d_out;                   // 128^3 floats

    unsigned* wq_dw  = (unsigned*)d_ws;                        // 25.17 MB quads
    unsigned* derivp = wq_dw + (size_t)NPROJ * NPIX * 4;       // 7.08 MB pairs

    k_deriv<<<dim3(NPROJ * NANG), dim3(192), 0, stream>>>(sino, wgt, derivp);
    k_bp2d <<<dim3(NPROJ, 32),    dim3(256), 0, stream>>>(derivp, wq_dw);
    k_bp3d_q<<<dim3(64, 32),      dim3(256), 0, stream>>>((const uint4*)wq_dw, prelu, out);
}